// Round 5
// baseline (330.745 us; speedup 1.0000x reference)
//
#include <hip/hip_runtime.h>
#include <math.h>

#define NP 20000
#define NG 5000
#define NTOT 25000
#define DF 512
#define NCLS 1000
#define DH 128
#define EPP 240000
#define EPG 100000
#define EGP 100000
#define ETOT 440000
#define FS 16   // fill stride (one counter per 64B line)

typedef __attribute__((ext_vector_type(8))) __bf16 bf16x8;
typedef __attribute__((ext_vector_type(4))) float f32x4;

// async global->LDS, 16B per lane; LDS dest = wave-uniform base + lane*16
__device__ __forceinline__ void gl2lds16(const void* g, void* l) {
    __builtin_amdgcn_global_load_lds(
        (const __attribute__((address_space(1))) unsigned int*)g,
        (__attribute__((address_space(3))) unsigned int*)l, 16, 0, 0);
}

__device__ __forceinline__ float b2f(unsigned short u) {
    union { unsigned int i; float f; } c; c.i = ((unsigned int)u) << 16; return c.f;
}

// ---------------- zero-atomic degree histograms ----------------
// One block per (array, bin-range) job: LDS-private bins, exact counts, plain stores.
__global__ __launch_bounds__(1024) void hist_priv_kernel(
    const int* __restrict__ src_pp, const int* __restrict__ dst_pp,
    const int* __restrict__ src_pg, const int* __restrict__ dst_pg,
    const int* __restrict__ src_gp, const int* __restrict__ dst_gp,
    int* __restrict__ outdeg_pp, int* __restrict__ indeg_pp,
    int* __restrict__ outdeg_pg, int* __restrict__ indeg_pg,
    int* __restrict__ outdeg_gp, int* __restrict__ indeg_gp)
{
    __shared__ int bins[10016];
    const int* idx; int* outarr; int lo, nbins, nedge;
    switch (blockIdx.y) {
    case 0: idx = src_pp; outarr = outdeg_pp; lo = 0;     nbins = 10000; nedge = EPP; break;
    case 1: idx = src_pp; outarr = outdeg_pp; lo = 10000; nbins = 10000; nedge = EPP; break;
    case 2: idx = dst_pp; outarr = indeg_pp;  lo = 0;     nbins = 10000; nedge = EPP; break;
    case 3: idx = dst_pp; outarr = indeg_pp;  lo = 10000; nbins = 10000; nedge = EPP; break;
    case 4: idx = src_pg; outarr = outdeg_pg; lo = 0;     nbins = 10000; nedge = EPG; break;
    case 5: idx = src_pg; outarr = outdeg_pg; lo = 10000; nbins = 10000; nedge = EPG; break;
    case 6: idx = dst_pg; outarr = indeg_pg;  lo = 0;     nbins = 5000;  nedge = EPG; break;
    case 7: idx = src_gp; outarr = outdeg_gp; lo = 0;     nbins = 5000;  nedge = EGP; break;
    case 8: idx = dst_gp; outarr = indeg_gp;  lo = 0;     nbins = 10000; nedge = EGP; break;
    default: idx = dst_gp; outarr = indeg_gp; lo = 10000; nbins = 10000; nedge = EGP; break;
    }
    for (int i = threadIdx.x; i < nbins; i += 1024) bins[i] = 0;
    __syncthreads();
    for (int e = threadIdx.x; e < nedge; e += 1024) {
        int b = idx[e] - lo;
        if ((unsigned)b < (unsigned)nbins) atomicAdd(&bins[b], 1);
    }
    __syncthreads();
    for (int i = threadIdx.x; i < nbins; i += 1024) outarr[lo + i] = bins[i];
}

// ---------------- exclusive scan of homogeneous in-degrees -> row_ptr[NTOT+1] ----------------
__global__ __launch_bounds__(1024) void scan_kernel(const int* __restrict__ indeg_pp,
                                                    const int* __restrict__ indeg_gp,
                                                    const int* __restrict__ indeg_pg,
                                                    int* __restrict__ row_ptr)
{
    __shared__ int part[1024];
    int t = threadIdx.x;
    const int CH = (NTOT + 1023) / 1024;  // 25
    int base = t * CH;
    auto cntf = [&](int idx) -> int {
        return (idx < NP) ? (indeg_pp[idx] + indeg_gp[idx]) : indeg_pg[idx - NP];
    };
    int s = 0;
    for (int i = 0; i < CH; i++) { int idx = base + i; if (idx < NTOT) s += cntf(idx); }
    part[t] = s;
    __syncthreads();
    for (int off = 1; off < 1024; off <<= 1) {
        int v = (t >= off) ? part[t - off] : 0;
        __syncthreads();
        part[t] += v;
        __syncthreads();
    }
    int run = (t == 0) ? 0 : part[t - 1];
    for (int i = 0; i < CH; i++) {
        int idx = base + i;
        if (idx < NTOT) { row_ptr[idx] = run; run += cntf(idx); }
    }
    if (t == 1023) row_ptr[NTOT] = part[1023];
}

// ---------------- scatter edges into CSR: single int2{payload, escale_bits} store ----------------
__global__ void scatter_kernel(const int* __restrict__ src_pp, const int* __restrict__ dst_pp,
                               const int* __restrict__ src_pg, const int* __restrict__ dst_pg,
                               const int* __restrict__ src_gp, const int* __restrict__ dst_gp,
                               const int* __restrict__ outdeg_pp, const int* __restrict__ outdeg_pg,
                               const int* __restrict__ outdeg_gp,
                               const int* __restrict__ row_ptr, int* fill,
                               int2* __restrict__ edata)
{
    int e = blockIdx.x * blockDim.x + threadIdx.x;
    int s, d, t; float sc;
    if (e < EPP) {
        s = src_pp[e]; d = dst_pp[e]; t = 0;
        sc = rsqrtf((float)max(outdeg_pp[s], 1));
    } else if (e < EPP + EPG) {
        int i = e - EPP; s = src_pg[i]; d = NP + dst_pg[i]; t = 1;
        sc = rsqrtf((float)max(outdeg_pg[s], 1));
    } else if (e < ETOT) {
        int i = e - EPP - EPG; int sl = src_gp[i]; s = NP + sl; d = dst_gp[i]; t = 2;
        sc = rsqrtf((float)max(outdeg_gp[sl], 1));
    } else return;
    int pos = row_ptr[d] + atomicAdd(&fill[d * FS], 1);
    edata[pos] = make_int2(s | (t << 16), __float_as_int(sc));
}

// ---------------- pack inputs to padded bf16 ----------------
__global__ __launch_bounds__(256) void conv_x_kernel(const float* __restrict__ xp, const float* __restrict__ xg,
                                                     __bf16* __restrict__ xpb, __bf16* __restrict__ xgb)
{
    long long e = ((long long)blockIdx.x * 256 + threadIdx.x) * 8;
    __bf16 pk[8];
    if (blockIdx.y == 0) {
        if (e >= (long long)20032 * 512) return;
        int row = (int)(e >> 9), k = (int)(e & 511);
        if (row < NP) {
            f32x4 v0 = *(const f32x4*)(xp + (size_t)row * 512 + k);
            f32x4 v1 = *(const f32x4*)(xp + (size_t)row * 512 + k + 4);
#pragma unroll
            for (int i = 0; i < 4; i++) { pk[i] = (__bf16)v0[i]; pk[4 + i] = (__bf16)v1[i]; }
        } else {
#pragma unroll
            for (int i = 0; i < 8; i++) pk[i] = (__bf16)0.f;
        }
        *(bf16x8*)(xpb + e) = *(bf16x8*)pk;
    } else {
        if (e >= (long long)5056 * 1024) return;
        int row = (int)(e >> 10), k = (int)(e & 1023);
        if (row < NG && k + 7 < 1000) {
            f32x4 v0 = *(const f32x4*)(xg + (size_t)row * 1000 + k);
            f32x4 v1 = *(const f32x4*)(xg + (size_t)row * 1000 + k + 4);
#pragma unroll
            for (int i = 0; i < 4; i++) { pk[i] = (__bf16)v0[i]; pk[4 + i] = (__bf16)v1[i]; }
        } else {
#pragma unroll
            for (int i = 0; i < 8; i++) {
                int kk = k + i;
                pk[i] = (__bf16)((row < NG && kk < 1000) ? xg[(size_t)row * 1000 + kk] : 0.f);
            }
        }
        *(bf16x8*)(xgb + e) = *(bf16x8*)pk;
    }
}

// ---------------- transpose weights to k-major bf16 [N][K] (padded, zero-filled) ----------------
__global__ __launch_bounds__(256) void conv_w_kernel(
    const float* W1p, const float* W1g, const float* Wlp, const float* Wrp, const float* Wrg,
    const float* Wnl, const float* Wnr, const float* Wfc,
    __bf16* w1pt, __bf16* w1gt, __bf16* wlpt, __bf16* wrpt, __bf16* wrgt,
    __bf16* wnlt, __bf16* wnrt, __bf16* wfct)
{
    int e = blockIdx.x * 256 + threadIdx.x;
    switch (blockIdx.y) {
    case 0: if (e < 128 * 512)  { int n = e >> 9, k = e & 511;  w1pt[e] = (__bf16)W1p[(size_t)k * 128 + n]; } break;
    case 1: if (e < 128 * 1024) { int n = e >> 10, k = e & 1023; w1gt[e] = (__bf16)(k < 1000 ? W1g[(size_t)k * 128 + n] : 0.f); } break;
    case 2: if (e < 16384) { int n = e >> 7, k = e & 127; wlpt[e] = (__bf16)Wlp[(size_t)k * 128 + n]; } break;
    case 3: if (e < 16384) { int n = e >> 7, k = e & 127; wrpt[e] = (__bf16)Wrp[(size_t)k * 128 + n]; } break;
    case 4: if (e < 16384) { int n = e >> 7, k = e & 127; wrgt[e] = (__bf16)Wrg[(size_t)k * 128 + n]; } break;
    case 5: if (e < 16384) { int n = e >> 7, k = e & 127; wnlt[e] = (__bf16)Wnl[(size_t)k * 128 + n]; } break;
    case 6: if (e < 16384) { int n = e >> 7, k = e & 127; wnrt[e] = (__bf16)Wnr[(size_t)k * 128 + n]; } break;
    case 7: if (e < 1024 * 128) { int n = e >> 7, k = e & 127; wfct[e] = (__bf16)(n < 1000 ? Wfc[(size_t)k * 1000 + n] : 0.f); } break;
    }
}

// =====================================================================
// MFMA bf16 GEMM with global_load_lds staging (m97 structure).
//   ACT: 0 none, 1 ELU, 2 row-l2norm (N==128, gridDim.y==1)
//   DUALA: acc += A2@B2 (bias=b1+b2);  DUALW: O2 = A1@B2 + b2 (fp32)
//   EMIT: 0 -> O1 fp32; 1 -> O1 fp32 + Ob bf16; 2 -> Ob bf16 only
// =====================================================================
struct GJob {
    const __bf16* A1; const __bf16* A2;
    const __bf16* B1; const __bf16* B2;
    const float* b1; const float* b2;
    float* O1; float* O2; __bf16* Ob;
    int M, N, Kp, ksteps;
};

template<int ACT, int DUALA, int DUALW, int EMIT>
__global__ __launch_bounds__(256) void gemm_bt(GJob j0, GJob j1, int split)
{
    __shared__ __align__(16) __bf16 As[64 * 32];
    __shared__ __align__(16) __bf16 A2s[DUALA ? 64 * 32 : 8];
    __shared__ __align__(16) __bf16 Bs[128 * 32];
    __shared__ __align__(16) __bf16 B2s[(DUALA || DUALW) ? 128 * 32 : 8];
    __shared__ float part[2][64];

    GJob j; int bx;
    if ((int)blockIdx.x < split) { j = j0; bx = blockIdx.x; }
    else { j = j1; bx = blockIdx.x - split; }

    const int tid = threadIdx.x;
    const int wave = tid >> 6, lane = tid & 63;
    const int wr = wave >> 1, wc = wave & 1;
    const int l15 = lane & 15, lh = lane >> 4;
    const int row0 = bx * 64;
    const int col0 = blockIdx.y * 128;

    const size_t aoff = (size_t)(row0 + (tid >> 2)) * j.Kp + (tid & 3) * 8;
    const size_t boff0 = (size_t)(col0 + (tid >> 2)) * j.Kp + (tid & 3) * 8;
    const size_t boff1 = boff0 + (size_t)64 * j.Kp;
    char* alds  = (char*)As + wave * 1024;
    char* a2lds = (char*)A2s + wave * 1024;
    char* blds0 = (char*)Bs + wave * 1024;
    char* blds1 = (char*)Bs + 4096 + wave * 1024;
    char* b2lds0 = (char*)B2s + wave * 1024;
    char* b2lds1 = (char*)B2s + 4096 + wave * 1024;

    f32x4 acc[2][4], acc2[2][4];
#pragma unroll
    for (int fm = 0; fm < 2; fm++)
#pragma unroll
        for (int fn = 0; fn < 4; fn++) {
            acc[fm][fn] = (f32x4)0.f;
            if (DUALW) acc2[fm][fn] = (f32x4)0.f;
        }

    for (int ks = 0; ks < j.ksteps; ks++) {
        const int k0 = ks * 32;
        __syncthreads();
        gl2lds16(j.A1 + aoff + k0, alds);
        if (DUALA) gl2lds16(j.A2 + aoff + k0, a2lds);
        gl2lds16(j.B1 + boff0 + k0, blds0);
        gl2lds16(j.B1 + boff1 + k0, blds1);
        if (DUALA || DUALW) {
            gl2lds16(j.B2 + boff0 + k0, b2lds0);
            gl2lds16(j.B2 + boff1 + k0, b2lds1);
        }
        __syncthreads();

#pragma unroll
        for (int fm = 0; fm < 2; fm++) {
            bf16x8 a = *(const bf16x8*)&As[(wr * 32 + fm * 16 + l15) * 32 + lh * 8];
            bf16x8 a2;
            if (DUALA) a2 = *(const bf16x8*)&A2s[(wr * 32 + fm * 16 + l15) * 32 + lh * 8];
#pragma unroll
            for (int fn = 0; fn < 4; fn++) {
                bf16x8 b = *(const bf16x8*)&Bs[(wc * 64 + fn * 16 + l15) * 32 + lh * 8];
                acc[fm][fn] = __builtin_amdgcn_mfma_f32_16x16x32_bf16(a, b, acc[fm][fn], 0, 0, 0);
                if (DUALA) {
                    bf16x8 b2 = *(const bf16x8*)&B2s[(wc * 64 + fn * 16 + l15) * 32 + lh * 8];
                    acc[fm][fn] = __builtin_amdgcn_mfma_f32_16x16x32_bf16(a2, b2, acc[fm][fn], 0, 0, 0);
                }
                if (DUALW) {
                    bf16x8 b2 = *(const bf16x8*)&B2s[(wc * 64 + fn * 16 + l15) * 32 + lh * 8];
                    acc2[fm][fn] = __builtin_amdgcn_mfma_f32_16x16x32_bf16(a, b2, acc2[fm][fn], 0, 0, 0);
                }
            }
        }
    }

    // ---- epilogue ----
    float bias[4], bias2[4];
#pragma unroll
    for (int fn = 0; fn < 4; fn++) {
        int col = col0 + wc * 64 + fn * 16 + l15;
        bias[fn] = 0.f; bias2[fn] = 0.f;
        if (col < j.N) {
            bias[fn] = DUALA ? (j.b1[col] + j.b2[col]) : j.b1[col];
            if (DUALW) bias2[fn] = j.b2[col];
        }
    }

    float vv[2][4][4];
#pragma unroll
    for (int fm = 0; fm < 2; fm++)
#pragma unroll
        for (int fn = 0; fn < 4; fn++)
#pragma unroll
            for (int r = 0; r < 4; r++) {
                float v = acc[fm][fn][r] + bias[fn];
                if (ACT == 1) v = v > 0.f ? v : (expf(v) - 1.f);
                vv[fm][fn][r] = v;
            }

    float scale[2][4];
#pragma unroll
    for (int fm = 0; fm < 2; fm++)
#pragma unroll
        for (int r = 0; r < 4; r++) scale[fm][r] = 1.f;

    if (ACT == 2) {
        float s[2][4];
#pragma unroll
        for (int fm = 0; fm < 2; fm++)
#pragma unroll
            for (int r = 0; r < 4; r++) {
                float v = 0.f;
#pragma unroll
                for (int fn = 0; fn < 4; fn++) v += vv[fm][fn][r] * vv[fm][fn][r];
                v += __shfl_xor(v, 1);
                v += __shfl_xor(v, 2);
                v += __shfl_xor(v, 4);
                v += __shfl_xor(v, 8);
                s[fm][r] = v;
            }
        __syncthreads();
        if (l15 == 0) {
#pragma unroll
            for (int fm = 0; fm < 2; fm++)
#pragma unroll
                for (int r = 0; r < 4; r++)
                    part[wc][wr * 32 + fm * 16 + lh * 4 + r] = s[fm][r];
        }
        __syncthreads();
#pragma unroll
        for (int fm = 0; fm < 2; fm++)
#pragma unroll
            for (int r = 0; r < 4; r++) {
                int rl = wr * 32 + fm * 16 + lh * 4 + r;
                float ss = part[0][rl] + part[1][rl];
                scale[fm][r] = 1.f / fmaxf(sqrtf(ss), 1e-12f);
            }
    }

#pragma unroll
    for (int fm = 0; fm < 2; fm++)
#pragma unroll
        for (int fn = 0; fn < 4; fn++)
#pragma unroll
            for (int r = 0; r < 4; r++) {
                int row = row0 + wr * 32 + fm * 16 + lh * 4 + r;
                int col = col0 + wc * 64 + fn * 16 + l15;
                if (row < j.M && col < j.N) {
                    float v = vv[fm][fn][r] * scale[fm][r];
                    if (EMIT != 2) j.O1[(size_t)row * j.N + col] = v;
                    if (EMIT != 0) j.Ob[(size_t)row * j.N + col] = (__bf16)v;
                    if (DUALW) j.O2[(size_t)row * j.N + col] = acc2[fm][fn][r] + bias2[fn];
                }
            }
}

// ---------------- GCN aggregation onto protein dst nodes (bf16 gather, bf16 out) ----------------
__global__ __launch_bounds__(128) void rst_agg_kernel(const __bf16* __restrict__ x,
                                                      const int* __restrict__ row_ptr,
                                                      const int2* __restrict__ edata,
                                                      const int* __restrict__ indeg_pp,
                                                      const int* __restrict__ indeg_gp,
                                                      __bf16* __restrict__ rppb, __bf16* __restrict__ rgpb)
{
    int d = blockIdx.x;  // < NP
    int c = threadIdx.x;
    int beg = row_ptr[d], end = row_ptr[d + 1];
    float spp = 0.f, sgp = 0.f;
    __shared__ int pl[128];
    __shared__ float sc[128];
    const unsigned short* xu = (const unsigned short*)x;
    for (int base = beg; base < end; base += 128) {
        int n = min(128, end - base);
        __syncthreads();
        if (c < n) { int2 e2 = edata[base + c]; pl[c] = e2.x; sc[c] = __int_as_float(e2.y); }
        __syncthreads();
        for (int i = 0; i < n; i++) {
            int p = pl[i]; int s = p & 0xFFFF; int t = p >> 16;
            float v = b2f(xu[(size_t)s * DH + c]) * sc[i];
            if (t == 0) spp += v; else sgp += v;
        }
    }
    float ipp = rsqrtf((float)max(indeg_pp[d], 1));
    float igp = rsqrtf((float)max(indeg_gp[d], 1));
    rppb[(size_t)d * DH + c] = (__bf16)(spp * ipp);
    rgpb[(size_t)d * DH + c] = (__bf16)(sgp * igp);
}

// ---------------- per-(protein,channel) type-level alpha weights, in-place ----------------
__global__ void wa_kernel(const int* __restrict__ indeg_pp, const int* __restrict__ indeg_gp,
                          float* __restrict__ eapp, float* __restrict__ eagp)
{
    int idx = blockIdx.x * blockDim.x + threadIdx.x;
    if (idx >= NP * DH) return;
    int d = idx >> 7;
    int npp = indeg_pp[d], ngp = indeg_gp[d];
    float app = eapp[idx], agp = eagp[idx];
    float wpp = 0.f, wgp = 0.f;
    if (npp > 0 && ngp > 0) {
        float mx = fmaxf(app, agp);
        float epp = __expf(app - mx), egp = __expf(agp - mx);
        float den = (float)npp * epp + (float)ngp * egp;
        wpp = epp / den; wgp = egp / den;
    } else if (npp > 0) wpp = 1.f / (float)npp;
    else if (ngp > 0) wgp = 1.f / (float)ngp;
    eapp[idx] = wpp;
    eagp[idx] = wgp;
}

// ---------------- node attention: branchless softmax (no max shift; |e| <= ~2) ----------------
__global__ __launch_bounds__(128) void node_attn_kernel(const __bf16* __restrict__ x,
                                                        const __bf16* __restrict__ hlb,
                                                        const float* __restrict__ hr,
                                                        const float* __restrict__ wpp_arr, const float* __restrict__ wgp_arr,
                                                        const int* __restrict__ indeg_pg,
                                                        const int* __restrict__ row_ptr, const int2* __restrict__ edata,
                                                        __bf16* __restrict__ hb)
{
    int d = blockIdx.x, c = threadIdx.x;
    int beg = row_ptr[d], end = row_ptr[d + 1];
    float hrd = hr[(size_t)d * DH + c];
    float wpp = 0.f, wgp = 0.f;
    if (d < NP) {
        wpp = wpp_arr[(size_t)d * DH + c];
        wgp = wgp_arr[(size_t)d * DH + c];
    } else {
        float wpg = 1.f / (float)max(indeg_pg[d - NP], 1);
        wpp = wpg; wgp = wpg;
    }
    float ssum = 0.f, acc = 0.f;
    __shared__ int pl[128];
    const unsigned short* xu = (const unsigned short*)x;
    const unsigned short* hu = (const unsigned short*)hlb;
    for (int base = beg; base < end; base += 128) {
        int n = min(128, end - base);
        __syncthreads();
        if (c < n) pl[c] = edata[base + c].x;
        __syncthreads();
        for (int i = 0; i < n; i++) {
            int p = pl[i]; int s = p & 0xFFFF; int t = p >> 16;
            float al = (t == 0) ? wpp : wgp;   // pp vs {gp,pg}; go-dst: both equal wpg
            float e = (b2f(hu[(size_t)s * DH + c]) + hrd) * al;
            e = fmaxf(e, -0.2f * e);           // LeakyReLU slope -0.2
            float pw = __expf(e);
            float xv = b2f(xu[(size_t)s * DH + c]);
            ssum += pw;
            acc += pw * xv;
        }
    }
    hb[(size_t)d * DH + c] = (__bf16)((end > beg) ? acc / ssum : 0.f);
}

extern "C" void kernel_launch(void* const* d_in, const int* in_sizes, int n_in,
                              void* d_out, int out_size, void* d_ws, size_t ws_size,
                              hipStream_t stream)
{
    const float* x_protein = (const float*)d_in[0];
    const float* x_go      = (const float*)d_in[1];
    const int* src_pp = (const int*)d_in[2];
    const int* dst_pp = (const int*)d_in[3];
    const int* src_pg = (const int*)d_in[4];
    const int* dst_pg = (const int*)d_in[5];
    const int* src_gp = (const int*)d_in[6];
    const int* dst_gp = (const int*)d_in[7];
    const float* W1p = (const float*)d_in[8];
    const float* b1p = (const float*)d_in[9];
    const float* W1g = (const float*)d_in[10];
    const float* b1g = (const float*)d_in[11];
    const float* Wl_p = (const float*)d_in[12];
    const float* bl_p = (const float*)d_in[13];
    // Wl_g (14), bl_g (15) dead: go-dst type-alpha is uniform 1/n
    const float* Wr_p = (const float*)d_in[16];
    const float* br_p = (const float*)d_in[17];
    const float* Wr_g = (const float*)d_in[18];
    const float* br_g = (const float*)d_in[19];
    const float* Wnl = (const float*)d_in[20];
    const float* bnl = (const float*)d_in[21];
    const float* Wnr = (const float*)d_in[22];
    const float* bnr = (const float*)d_in[23];
    const float* Wfc = (const float*)d_in[24];
    const float* bfc = (const float*)d_in[25];
    float* out = (float*)d_out;

    // ---- workspace layout (4B words, 16B-aligned blocks); total ~74 MB ----
    size_t off = 0;
    char* base = (char*)d_ws;
    auto alloc = [&](size_t words) { void* p = base + off * 4; off += (words + 7) & ~(size_t)7; return p; };

    __bf16* xb   = (__bf16*)alloc((size_t)25024 * 128 / 2);
    float*  hr   = (float*)alloc((size_t)25000 * 128);
    __bf16* hlb  = (__bf16*)alloc((size_t)25024 * 128 / 2);
    __bf16* rppb = (__bf16*)alloc((size_t)20032 * 128 / 2);
    __bf16* rgpb = (__bf16*)alloc((size_t)20032 * 128 / 2);
    // R1: xpb+xgb during proj; wpp,wgp,haggb after
    char* R1 = (char*)alloc((size_t)5128192 + 2588672);
    __bf16* xpb = (__bf16*)R1;                             // 20032*512
    __bf16* xgb = (__bf16*)(R1 + (size_t)20032 * 512 * 2); // 5056*1024
    float*  wpp = (float*)R1;                              // 20000*128
    float*  wgp = wpp + (size_t)20000 * 128;
    __bf16* haggb = (__bf16*)(wgp + (size_t)20000 * 128);  // 25024*128
    __bf16* w1pt = (__bf16*)alloc(128 * 512 / 2);
    __bf16* w1gt = (__bf16*)alloc(128 * 1024 / 2);
    __bf16* wlpt = (__bf16*)alloc(128 * 128 / 2);
    __bf16* wrpt = (__bf16*)alloc(128 * 128 / 2);
    __bf16* wrgt = (__bf16*)alloc(128 * 128 / 2);
    __bf16* wnlt = (__bf16*)alloc(128 * 128 / 2);
    __bf16* wnrt = (__bf16*)alloc(128 * 128 / 2);
    __bf16* wfct = (__bf16*)alloc(1024 * 128 / 2);
    int* outdeg_pp = (int*)alloc(NP);
    int* outdeg_pg = (int*)alloc(NP);
    int* outdeg_gp = (int*)alloc(NG);
    int* indeg_pp  = (int*)alloc(NP);
    int* indeg_gp  = (int*)alloc(NP);
    int* indeg_pg  = (int*)alloc(NG);
    int* fill      = (int*)alloc((size_t)NTOT * FS);
    int* row_ptr   = (int*)alloc(NTOT + 1);
    int2* edata    = (int2*)alloc((size_t)ETOT * 2);

    // zero only the fill counters (degree arrays are fully overwritten by hist_priv)
    hipMemsetAsync(fill, 0, (size_t)NTOT * FS * sizeof(int), stream);

    hist_priv_kernel<<<dim3(1, 10), 1024, 0, stream>>>(
        src_pp, dst_pp, src_pg, dst_pg, src_gp, dst_gp,
        outdeg_pp, indeg_pp, outdeg_pg, indeg_pg, outdeg_gp, indeg_gp);
    scan_kernel<<<1, 1024, 0, stream>>>(indeg_pp, indeg_gp, indeg_pg, row_ptr);
    scatter_kernel<<<(ETOT + 255) / 256, 256, 0, stream>>>(
        src_pp, dst_pp, src_pg, dst_pg, src_gp, dst_gp,
        outdeg_pp, outdeg_pg, outdeg_gp, row_ptr, fill, edata);

    conv_x_kernel<<<dim3(5008, 2), 256, 0, stream>>>(x_protein, x_go, xpb, xgb);
    conv_w_kernel<<<dim3(512, 8), 256, 0, stream>>>(W1p, W1g, Wl_p, Wr_p, Wr_g, Wnl, Wnr, Wfc,
                                                    w1pt, w1gt, wlpt, wrpt, wrgt, wnlt, wnrt, wfct);

    // fused projections + l2norm -> xb (bf16): blocks [0,313) protein, [313,392) go
    {
        GJob p0 = { xpb, nullptr, w1pt, nullptr, b1p, nullptr, nullptr, nullptr, xb, NP, 128, 512, 16 };
        GJob p1 = { xgb, nullptr, w1gt, nullptr, b1g, nullptr, nullptr, nullptr,
                    xb + (size_t)NP * 128, NG, 128, 1024, 32 };
        gemm_bt<2, 0, 0, 2><<<392, 256, 0, stream>>>(p0, p1, 313);
    }

    // GCN aggregation for type attention (protein dst only)
    rst_agg_kernel<<<NP, 128, 0, stream>>>(xb, row_ptr, edata, indeg_pp, indeg_gp, rppb, rgpb);

    // fused ea: wpp = elu(x@Wl_p + rpp@Wr_p + ...); wgp = elu(x@Wl_p + rgp@Wr_g + ...)
    {
        GJob e0 = { xb, rppb, wlpt, wrpt, bl_p, br_p, wpp, nullptr, nullptr, NP, 128, 128, 4 };
        GJob e1 = { xb, rgpb, wlpt, wrgt, bl_p, br_g, wgp, nullptr, nullptr, NP, 128, 128, 4 };
        gemm_bt<1, 1, 0, 0><<<626, 256, 0, stream>>>(e0, e1, 313);
    }

    // type-level alpha weights (in-place over wpp/wgp)
    wa_kernel<<<(NP * DH + 255) / 256, 256, 0, stream>>>(indeg_pp, indeg_gp, wpp, wgp);

    // node attention projections: Ob(bf16) = x@Wnl+bnl = hl; O2(fp32) = x@Wnr+bnr = hr
    {
        GJob h0 = { xb, nullptr, wnlt, wnrt, bnl, bnr, nullptr, hr, hlb, NTOT, 128, 128, 4 };
        gemm_bt<0, 0, 1, 2><<<391, 256, 0, stream>>>(h0, h0, 1 << 30);
    }

    // node attention + aggregation -> haggb (bf16)
    node_attn_kernel<<<NTOT, 128, 0, stream>>>(xb, hlb, hr, wpp, wgp, indeg_pg, row_ptr, edata, haggb);

    // final classifier: out = hagg@Wfc + bfc
    {
        GJob o0 = { haggb, nullptr, wfct, nullptr, bfc, nullptr, out, nullptr, nullptr, NTOT, NCLS, 128, 4 };
        gemm_bt<0, 0, 0, 0><<<dim3(391, 8), 256, 0, stream>>>(o0, o0, 1 << 30);
    }

    (void)in_sizes; (void)n_in; (void)out_size; (void)ws_size;
}

// Round 6
// 264.251 us; speedup vs baseline: 1.2516x; 1.2516x over previous
//
#include <hip/hip_runtime.h>
#include <math.h>

#define NP 20000
#define NG 5000
#define NTOT 25000
#define DF 512
#define NCLS 1000
#define DH 128
#define EPP 240000
#define EPG 100000
#define EGP 100000
#define ETOT 440000
#define FS 16   // fill stride (one counter per 64B line)
#define HB 16   // partial-histogram blocks per job

typedef __attribute__((ext_vector_type(8))) __bf16 bf16x8;
typedef __attribute__((ext_vector_type(4))) float f32x4;

// async global->LDS, 16B per lane; LDS dest = wave-uniform base + lane*16
__device__ __forceinline__ void gl2lds16(const void* g, void* l) {
    __builtin_amdgcn_global_load_lds(
        (const __attribute__((address_space(1))) unsigned int*)g,
        (__attribute__((address_space(3))) unsigned int*)l, 16, 0, 0);
}

__device__ __forceinline__ float b2f(unsigned short u) {
    union { unsigned int i; float f; } c; c.i = ((unsigned int)u) << 16; return c.f;
}

// ---------------- partial histograms: HB blocks/job, LDS-private, plain stores ----------------
// partial layout (ints): job0 @0 [HB][20000], job1 @320000, job2 @640000,
//                        job3 @960000 [HB][5000], job4 @1040000 [HB][5000], job5 @1120000 [HB][20000]
__global__ __launch_bounds__(1024) void hist_part_kernel(
    const int* __restrict__ src_pp, const int* __restrict__ dst_pp,
    const int* __restrict__ src_pg, const int* __restrict__ dst_pg,
    const int* __restrict__ src_gp, const int* __restrict__ dst_gp,
    int* __restrict__ partial)
{
    __shared__ int bins[20000];
    const int job = blockIdx.y, b = blockIdx.x;
    const int* idx; int nbins, nedge; size_t pbase;
    switch (job) {
    case 0: idx = src_pp; nbins = 20000; nedge = EPP; pbase = 0;       break;
    case 1: idx = dst_pp; nbins = 20000; nedge = EPP; pbase = 320000;  break;
    case 2: idx = src_pg; nbins = 20000; nedge = EPG; pbase = 640000;  break;
    case 3: idx = dst_pg; nbins = 5000;  nedge = EPG; pbase = 960000;  break;
    case 4: idx = src_gp; nbins = 5000;  nedge = EGP; pbase = 1040000; break;
    default: idx = dst_gp; nbins = 20000; nedge = EGP; pbase = 1120000; break;
    }
    for (int i = threadIdx.x; i < nbins; i += 1024) bins[i] = 0;
    __syncthreads();
    const int chunk = (nedge + HB - 1) / HB;
    const int e0 = b * chunk, e1 = min(e0 + chunk, nedge);
    for (int e = e0 + threadIdx.x; e < e1; e += 1024) atomicAdd(&bins[idx[e]], 1);
    __syncthreads();
    int* dst = partial + pbase + (size_t)b * nbins;
    for (int i = threadIdx.x; i < nbins; i += 1024) dst[i] = bins[i];
}

// ---------------- merge partials -> degree arrays (plain coalesced) ----------------
__global__ __launch_bounds__(256) void hist_merge_kernel(const int* __restrict__ partial,
    int* __restrict__ outdeg_pp, int* __restrict__ indeg_pp,
    int* __restrict__ outdeg_pg, int* __restrict__ indeg_pg,
    int* __restrict__ outdeg_gp, int* __restrict__ indeg_gp)
{
    const int job = blockIdx.y;
    const int nbins = (job == 3 || job == 4) ? 5000 : 20000;
    const int bin = blockIdx.x * 256 + threadIdx.x;
    if (bin >= nbins) return;
    size_t pbase;
    int* outp;
    switch (job) {
    case 0: pbase = 0;       outp = outdeg_pp; break;
    case 1: pbase = 320000;  outp = indeg_pp;  break;
    case 2: pbase = 640000;  outp = outdeg_pg; break;
    case 3: pbase = 960000;  outp = indeg_pg;  break;
    case 4: pbase = 1040000; outp = outdeg_gp; break;
    default: pbase = 1120000; outp = indeg_gp; break;
    }
    const int* p = partial + pbase + bin;
    int s = 0;
#pragma unroll
    for (int b = 0; b < HB; b++) s += p[(size_t)b * nbins];
    outp[bin] = s;
}

// ---------------- exclusive scan of homogeneous in-degrees -> row_ptr[NTOT+1] ----------------
__global__ __launch_bounds__(1024) void scan_kernel(const int* __restrict__ indeg_pp,
                                                    const int* __restrict__ indeg_gp,
                                                    const int* __restrict__ indeg_pg,
                                                    int* __restrict__ row_ptr)
{
    __shared__ int part[1024];
    int t = threadIdx.x;
    const int CH = (NTOT + 1023) / 1024;  // 25
    int base = t * CH;
    auto cntf = [&](int idx) -> int {
        return (idx < NP) ? (indeg_pp[idx] + indeg_gp[idx]) : indeg_pg[idx - NP];
    };
    int s = 0;
    for (int i = 0; i < CH; i++) { int idx = base + i; if (idx < NTOT) s += cntf(idx); }
    part[t] = s;
    __syncthreads();
    for (int off = 1; off < 1024; off <<= 1) {
        int v = (t >= off) ? part[t - off] : 0;
        __syncthreads();
        part[t] += v;
        __syncthreads();
    }
    int run = (t == 0) ? 0 : part[t - 1];
    for (int i = 0; i < CH; i++) {
        int idx = base + i;
        if (idx < NTOT) { row_ptr[idx] = run; run += cntf(idx); }
    }
    if (t == 1023) row_ptr[NTOT] = part[1023];
}

// ---------------- scatter edges into CSR: single int2{payload, escale_bits} store ----------------
__global__ void scatter_kernel(const int* __restrict__ src_pp, const int* __restrict__ dst_pp,
                               const int* __restrict__ src_pg, const int* __restrict__ dst_pg,
                               const int* __restrict__ src_gp, const int* __restrict__ dst_gp,
                               const int* __restrict__ outdeg_pp, const int* __restrict__ outdeg_pg,
                               const int* __restrict__ outdeg_gp,
                               const int* __restrict__ row_ptr, int* fill,
                               int2* __restrict__ edata)
{
    int e = blockIdx.x * blockDim.x + threadIdx.x;
    int s, d, t; float sc;
    if (e < EPP) {
        s = src_pp[e]; d = dst_pp[e]; t = 0;
        sc = rsqrtf((float)max(outdeg_pp[s], 1));
    } else if (e < EPP + EPG) {
        int i = e - EPP; s = src_pg[i]; d = NP + dst_pg[i]; t = 1;
        sc = rsqrtf((float)max(outdeg_pg[s], 1));
    } else if (e < ETOT) {
        int i = e - EPP - EPG; int sl = src_gp[i]; s = NP + sl; d = dst_gp[i]; t = 2;
        sc = rsqrtf((float)max(outdeg_gp[sl], 1));
    } else return;
    int pos = row_ptr[d] + atomicAdd(&fill[d * FS], 1);
    edata[pos] = make_int2(s | (t << 16), __float_as_int(sc));
}

// ---------------- pack inputs to padded bf16 ----------------
__global__ __launch_bounds__(256) void conv_x_kernel(const float* __restrict__ xp, const float* __restrict__ xg,
                                                     __bf16* __restrict__ xpb, __bf16* __restrict__ xgb)
{
    long long e = ((long long)blockIdx.x * 256 + threadIdx.x) * 8;
    __bf16 pk[8];
    if (blockIdx.y == 0) {
        if (e >= (long long)20032 * 512) return;
        int row = (int)(e >> 9), k = (int)(e & 511);
        if (row < NP) {
            f32x4 v0 = *(const f32x4*)(xp + (size_t)row * 512 + k);
            f32x4 v1 = *(const f32x4*)(xp + (size_t)row * 512 + k + 4);
#pragma unroll
            for (int i = 0; i < 4; i++) { pk[i] = (__bf16)v0[i]; pk[4 + i] = (__bf16)v1[i]; }
        } else {
#pragma unroll
            for (int i = 0; i < 8; i++) pk[i] = (__bf16)0.f;
        }
        *(bf16x8*)(xpb + e) = *(bf16x8*)pk;
    } else {
        if (e >= (long long)5056 * 1024) return;
        int row = (int)(e >> 10), k = (int)(e & 1023);
        if (row < NG && k + 7 < 1000) {
            f32x4 v0 = *(const f32x4*)(xg + (size_t)row * 1000 + k);
            f32x4 v1 = *(const f32x4*)(xg + (size_t)row * 1000 + k + 4);
#pragma unroll
            for (int i = 0; i < 4; i++) { pk[i] = (__bf16)v0[i]; pk[4 + i] = (__bf16)v1[i]; }
        } else {
#pragma unroll
            for (int i = 0; i < 8; i++) {
                int kk = k + i;
                pk[i] = (__bf16)((row < NG && kk < 1000) ? xg[(size_t)row * 1000 + kk] : 0.f);
            }
        }
        *(bf16x8*)(xgb + e) = *(bf16x8*)pk;
    }
}

// ---------------- transpose weights to k-major bf16 [N][K] (padded, zero-filled) ----------------
__global__ __launch_bounds__(256) void conv_w_kernel(
    const float* W1p, const float* W1g, const float* Wlp, const float* Wrp, const float* Wrg,
    const float* Wnl, const float* Wnr, const float* Wfc,
    __bf16* w1pt, __bf16* w1gt, __bf16* wlpt, __bf16* wrpt, __bf16* wrgt,
    __bf16* wnlt, __bf16* wnrt, __bf16* wfct)
{
    int e = blockIdx.x * 256 + threadIdx.x;
    switch (blockIdx.y) {
    case 0: if (e < 128 * 512)  { int n = e >> 9, k = e & 511;  w1pt[e] = (__bf16)W1p[(size_t)k * 128 + n]; } break;
    case 1: if (e < 128 * 1024) { int n = e >> 10, k = e & 1023; w1gt[e] = (__bf16)(k < 1000 ? W1g[(size_t)k * 128 + n] : 0.f); } break;
    case 2: if (e < 16384) { int n = e >> 7, k = e & 127; wlpt[e] = (__bf16)Wlp[(size_t)k * 128 + n]; } break;
    case 3: if (e < 16384) { int n = e >> 7, k = e & 127; wrpt[e] = (__bf16)Wrp[(size_t)k * 128 + n]; } break;
    case 4: if (e < 16384) { int n = e >> 7, k = e & 127; wrgt[e] = (__bf16)Wrg[(size_t)k * 128 + n]; } break;
    case 5: if (e < 16384) { int n = e >> 7, k = e & 127; wnlt[e] = (__bf16)Wnl[(size_t)k * 128 + n]; } break;
    case 6: if (e < 16384) { int n = e >> 7, k = e & 127; wnrt[e] = (__bf16)Wnr[(size_t)k * 128 + n]; } break;
    case 7: if (e < 1024 * 128) { int n = e >> 7, k = e & 127; wfct[e] = (__bf16)(n < 1000 ? Wfc[(size_t)k * 1000 + n] : 0.f); } break;
    }
}

// =====================================================================
// MFMA bf16 GEMM with global_load_lds staging (m97 structure).
//   ACT: 0 none, 1 ELU, 2 row-l2norm (N==128, gridDim.y==1)
//   DUALA: acc += A2@B2 (bias=b1+b2);  DUALW: O2 = A1@B2 + b2 (fp32)
//   EMIT: 0 -> O1 fp32; 1 -> O1 fp32 + Ob bf16; 2 -> Ob bf16 only
// =====================================================================
struct GJob {
    const __bf16* A1; const __bf16* A2;
    const __bf16* B1; const __bf16* B2;
    const float* b1; const float* b2;
    float* O1; float* O2; __bf16* Ob;
    int M, N, Kp, ksteps;
};

template<int ACT, int DUALA, int DUALW, int EMIT>
__global__ __launch_bounds__(256) void gemm_bt(GJob j0, GJob j1, int split)
{
    __shared__ __align__(16) __bf16 As[64 * 32];
    __shared__ __align__(16) __bf16 A2s[DUALA ? 64 * 32 : 8];
    __shared__ __align__(16) __bf16 Bs[128 * 32];
    __shared__ __align__(16) __bf16 B2s[(DUALA || DUALW) ? 128 * 32 : 8];
    __shared__ float part[2][64];

    GJob j; int bx;
    if ((int)blockIdx.x < split) { j = j0; bx = blockIdx.x; }
    else { j = j1; bx = blockIdx.x - split; }

    const int tid = threadIdx.x;
    const int wave = tid >> 6, lane = tid & 63;
    const int wr = wave >> 1, wc = wave & 1;
    const int l15 = lane & 15, lh = lane >> 4;
    const int row0 = bx * 64;
    const int col0 = blockIdx.y * 128;

    const size_t aoff = (size_t)(row0 + (tid >> 2)) * j.Kp + (tid & 3) * 8;
    const size_t boff0 = (size_t)(col0 + (tid >> 2)) * j.Kp + (tid & 3) * 8;
    const size_t boff1 = boff0 + (size_t)64 * j.Kp;
    char* alds  = (char*)As + wave * 1024;
    char* a2lds = (char*)A2s + wave * 1024;
    char* blds0 = (char*)Bs + wave * 1024;
    char* blds1 = (char*)Bs + 4096 + wave * 1024;
    char* b2lds0 = (char*)B2s + wave * 1024;
    char* b2lds1 = (char*)B2s + 4096 + wave * 1024;

    f32x4 acc[2][4], acc2[2][4];
#pragma unroll
    for (int fm = 0; fm < 2; fm++)
#pragma unroll
        for (int fn = 0; fn < 4; fn++) {
            acc[fm][fn] = (f32x4)0.f;
            if (DUALW) acc2[fm][fn] = (f32x4)0.f;
        }

    for (int ks = 0; ks < j.ksteps; ks++) {
        const int k0 = ks * 32;
        __syncthreads();
        gl2lds16(j.A1 + aoff + k0, alds);
        if (DUALA) gl2lds16(j.A2 + aoff + k0, a2lds);
        gl2lds16(j.B1 + boff0 + k0, blds0);
        gl2lds16(j.B1 + boff1 + k0, blds1);
        if (DUALA || DUALW) {
            gl2lds16(j.B2 + boff0 + k0, b2lds0);
            gl2lds16(j.B2 + boff1 + k0, b2lds1);
        }
        __syncthreads();

#pragma unroll
        for (int fm = 0; fm < 2; fm++) {
            bf16x8 a = *(const bf16x8*)&As[(wr * 32 + fm * 16 + l15) * 32 + lh * 8];
            bf16x8 a2;
            if (DUALA) a2 = *(const bf16x8*)&A2s[(wr * 32 + fm * 16 + l15) * 32 + lh * 8];
#pragma unroll
            for (int fn = 0; fn < 4; fn++) {
                bf16x8 b = *(const bf16x8*)&Bs[(wc * 64 + fn * 16 + l15) * 32 + lh * 8];
                acc[fm][fn] = __builtin_amdgcn_mfma_f32_16x16x32_bf16(a, b, acc[fm][fn], 0, 0, 0);
                if (DUALA) {
                    bf16x8 b2 = *(const bf16x8*)&B2s[(wc * 64 + fn * 16 + l15) * 32 + lh * 8];
                    acc[fm][fn] = __builtin_amdgcn_mfma_f32_16x16x32_bf16(a2, b2, acc[fm][fn], 0, 0, 0);
                }
                if (DUALW) {
                    bf16x8 b2 = *(const bf16x8*)&B2s[(wc * 64 + fn * 16 + l15) * 32 + lh * 8];
                    acc2[fm][fn] = __builtin_amdgcn_mfma_f32_16x16x32_bf16(a, b2, acc2[fm][fn], 0, 0, 0);
                }
            }
        }
    }

    // ---- epilogue ----
    float bias[4], bias2[4];
#pragma unroll
    for (int fn = 0; fn < 4; fn++) {
        int col = col0 + wc * 64 + fn * 16 + l15;
        bias[fn] = 0.f; bias2[fn] = 0.f;
        if (col < j.N) {
            bias[fn] = DUALA ? (j.b1[col] + j.b2[col]) : j.b1[col];
            if (DUALW) bias2[fn] = j.b2[col];
        }
    }

    float vv[2][4][4];
#pragma unroll
    for (int fm = 0; fm < 2; fm++)
#pragma unroll
        for (int fn = 0; fn < 4; fn++)
#pragma unroll
            for (int r = 0; r < 4; r++) {
                float v = acc[fm][fn][r] + bias[fn];
                if (ACT == 1) v = v > 0.f ? v : (expf(v) - 1.f);
                vv[fm][fn][r] = v;
            }

    float scale[2][4];
#pragma unroll
    for (int fm = 0; fm < 2; fm++)
#pragma unroll
        for (int r = 0; r < 4; r++) scale[fm][r] = 1.f;

    if (ACT == 2) {
        float s[2][4];
#pragma unroll
        for (int fm = 0; fm < 2; fm++)
#pragma unroll
            for (int r = 0; r < 4; r++) {
                float v = 0.f;
#pragma unroll
                for (int fn = 0; fn < 4; fn++) v += vv[fm][fn][r] * vv[fm][fn][r];
                v += __shfl_xor(v, 1);
                v += __shfl_xor(v, 2);
                v += __shfl_xor(v, 4);
                v += __shfl_xor(v, 8);
                s[fm][r] = v;
            }
        __syncthreads();
        if (l15 == 0) {
#pragma unroll
            for (int fm = 0; fm < 2; fm++)
#pragma unroll
                for (int r = 0; r < 4; r++)
                    part[wc][wr * 32 + fm * 16 + lh * 4 + r] = s[fm][r];
        }
        __syncthreads();
#pragma unroll
        for (int fm = 0; fm < 2; fm++)
#pragma unroll
            for (int r = 0; r < 4; r++) {
                int rl = wr * 32 + fm * 16 + lh * 4 + r;
                float ss = part[0][rl] + part[1][rl];
                scale[fm][r] = 1.f / fmaxf(sqrtf(ss), 1e-12f);
            }
    }

#pragma unroll
    for (int fm = 0; fm < 2; fm++)
#pragma unroll
        for (int fn = 0; fn < 4; fn++)
#pragma unroll
            for (int r = 0; r < 4; r++) {
                int row = row0 + wr * 32 + fm * 16 + lh * 4 + r;
                int col = col0 + wc * 64 + fn * 16 + l15;
                if (row < j.M && col < j.N) {
                    float v = vv[fm][fn][r] * scale[fm][r];
                    if (EMIT != 2) j.O1[(size_t)row * j.N + col] = v;
                    if (EMIT != 0) j.Ob[(size_t)row * j.N + col] = (__bf16)v;
                    if (DUALW) j.O2[(size_t)row * j.N + col] = acc2[fm][fn][r] + bias2[fn];
                }
            }
}

// ---------------- GCN aggregation onto protein dst nodes (bf16 gather, bf16 out) ----------------
__global__ __launch_bounds__(128) void rst_agg_kernel(const __bf16* __restrict__ x,
                                                      const int* __restrict__ row_ptr,
                                                      const int2* __restrict__ edata,
                                                      const int* __restrict__ indeg_pp,
                                                      const int* __restrict__ indeg_gp,
                                                      __bf16* __restrict__ rppb, __bf16* __restrict__ rgpb)
{
    int d = blockIdx.x;  // < NP
    int c = threadIdx.x;
    int beg = row_ptr[d], end = row_ptr[d + 1];
    float spp = 0.f, sgp = 0.f;
    __shared__ int pl[128];
    __shared__ float sc[128];
    const unsigned short* xu = (const unsigned short*)x;
    for (int base = beg; base < end; base += 128) {
        int n = min(128, end - base);
        __syncthreads();
        if (c < n) { int2 e2 = edata[base + c]; pl[c] = e2.x; sc[c] = __int_as_float(e2.y); }
        __syncthreads();
        for (int i = 0; i < n; i++) {
            int p = pl[i]; int s = p & 0xFFFF; int t = p >> 16;
            float v = b2f(xu[(size_t)s * DH + c]) * sc[i];
            if (t == 0) spp += v; else sgp += v;
        }
    }
    float ipp = rsqrtf((float)max(indeg_pp[d], 1));
    float igp = rsqrtf((float)max(indeg_gp[d], 1));
    rppb[(size_t)d * DH + c] = (__bf16)(spp * ipp);
    rgpb[(size_t)d * DH + c] = (__bf16)(sgp * igp);
}

// ---------------- per-(protein,channel) type-level alpha weights, in-place ----------------
__global__ void wa_kernel(const int* __restrict__ indeg_pp, const int* __restrict__ indeg_gp,
                          float* __restrict__ eapp, float* __restrict__ eagp)
{
    int idx = blockIdx.x * blockDim.x + threadIdx.x;
    if (idx >= NP * DH) return;
    int d = idx >> 7;
    int npp = indeg_pp[d], ngp = indeg_gp[d];
    float app = eapp[idx], agp = eagp[idx];
    float wpp = 0.f, wgp = 0.f;
    if (npp > 0 && ngp > 0) {
        float mx = fmaxf(app, agp);
        float epp = __expf(app - mx), egp = __expf(agp - mx);
        float den = (float)npp * epp + (float)ngp * egp;
        wpp = epp / den; wgp = egp / den;
    } else if (npp > 0) wpp = 1.f / (float)npp;
    else if (ngp > 0) wgp = 1.f / (float)ngp;
    eapp[idx] = wpp;
    eagp[idx] = wgp;
}

// ---------------- node attention: branchless softmax (no max shift; |e| <= ~2) ----------------
__global__ __launch_bounds__(128) void node_attn_kernel(const __bf16* __restrict__ x,
                                                        const __bf16* __restrict__ hlb,
                                                        const float* __restrict__ hr,
                                                        const float* __restrict__ wpp_arr, const float* __restrict__ wgp_arr,
                                                        const int* __restrict__ indeg_pg,
                                                        const int* __restrict__ row_ptr, const int2* __restrict__ edata,
                                                        __bf16* __restrict__ hb)
{
    int d = blockIdx.x, c = threadIdx.x;
    int beg = row_ptr[d], end = row_ptr[d + 1];
    float hrd = hr[(size_t)d * DH + c];
    float wpp = 0.f, wgp = 0.f;
    if (d < NP) {
        wpp = wpp_arr[(size_t)d * DH + c];
        wgp = wgp_arr[(size_t)d * DH + c];
    } else {
        float wpg = 1.f / (float)max(indeg_pg[d - NP], 1);
        wpp = wpg; wgp = wpg;
    }
    float ssum = 0.f, acc = 0.f;
    __shared__ int pl[128];
    const unsigned short* xu = (const unsigned short*)x;
    const unsigned short* hu = (const unsigned short*)hlb;
    for (int base = beg; base < end; base += 128) {
        int n = min(128, end - base);
        __syncthreads();
        if (c < n) pl[c] = edata[base + c].x;
        __syncthreads();
        for (int i = 0; i < n; i++) {
            int p = pl[i]; int s = p & 0xFFFF; int t = p >> 16;
            float al = (t == 0) ? wpp : wgp;   // pp vs {gp,pg}; go-dst: both equal wpg
            float e = (b2f(hu[(size_t)s * DH + c]) + hrd) * al;
            e = fmaxf(e, -0.2f * e);           // LeakyReLU slope -0.2
            float pw = __expf(e);
            float xv = b2f(xu[(size_t)s * DH + c]);
            ssum += pw;
            acc += pw * xv;
        }
    }
    hb[(size_t)d * DH + c] = (__bf16)((end > beg) ? acc / ssum : 0.f);
}

extern "C" void kernel_launch(void* const* d_in, const int* in_sizes, int n_in,
                              void* d_out, int out_size, void* d_ws, size_t ws_size,
                              hipStream_t stream)
{
    const float* x_protein = (const float*)d_in[0];
    const float* x_go      = (const float*)d_in[1];
    const int* src_pp = (const int*)d_in[2];
    const int* dst_pp = (const int*)d_in[3];
    const int* src_pg = (const int*)d_in[4];
    const int* dst_pg = (const int*)d_in[5];
    const int* src_gp = (const int*)d_in[6];
    const int* dst_gp = (const int*)d_in[7];
    const float* W1p = (const float*)d_in[8];
    const float* b1p = (const float*)d_in[9];
    const float* W1g = (const float*)d_in[10];
    const float* b1g = (const float*)d_in[11];
    const float* Wl_p = (const float*)d_in[12];
    const float* bl_p = (const float*)d_in[13];
    // Wl_g (14), bl_g (15) dead: go-dst type-alpha is uniform 1/n
    const float* Wr_p = (const float*)d_in[16];
    const float* br_p = (const float*)d_in[17];
    const float* Wr_g = (const float*)d_in[18];
    const float* br_g = (const float*)d_in[19];
    const float* Wnl = (const float*)d_in[20];
    const float* bnl = (const float*)d_in[21];
    const float* Wnr = (const float*)d_in[22];
    const float* bnr = (const float*)d_in[23];
    const float* Wfc = (const float*)d_in[24];
    const float* bfc = (const float*)d_in[25];
    float* out = (float*)d_out;

    // ---- workspace layout (4B words, 16B-aligned blocks); total ~74 MB ----
    size_t off = 0;
    char* base = (char*)d_ws;
    auto alloc = [&](size_t words) { void* p = base + off * 4; off += (words + 7) & ~(size_t)7; return p; };

    __bf16* xb   = (__bf16*)alloc((size_t)25024 * 128 / 2);
    float*  hr   = (float*)alloc((size_t)25000 * 128);
    __bf16* hlb  = (__bf16*)alloc((size_t)25024 * 128 / 2);
    __bf16* rppb = (__bf16*)alloc((size_t)20032 * 128 / 2);
    __bf16* rgpb = (__bf16*)alloc((size_t)20032 * 128 / 2);
    // R1 (7.7MB): hist partials (5.76MB) during preprocessing; xpb+xgb during proj; wpp,wgp,haggb after
    char* R1 = (char*)alloc((size_t)5128192 + 2588672);
    int*    partial = (int*)R1;                            // HB*90000 = 1.44M ints
    __bf16* xpb = (__bf16*)R1;                             // 20032*512
    __bf16* xgb = (__bf16*)(R1 + (size_t)20032 * 512 * 2); // 5056*1024
    float*  wpp = (float*)R1;                              // 20000*128
    float*  wgp = wpp + (size_t)20000 * 128;
    __bf16* haggb = (__bf16*)(wgp + (size_t)20000 * 128);  // 25024*128
    __bf16* w1pt = (__bf16*)alloc(128 * 512 / 2);
    __bf16* w1gt = (__bf16*)alloc(128 * 1024 / 2);
    __bf16* wlpt = (__bf16*)alloc(128 * 128 / 2);
    __bf16* wrpt = (__bf16*)alloc(128 * 128 / 2);
    __bf16* wrgt = (__bf16*)alloc(128 * 128 / 2);
    __bf16* wnlt = (__bf16*)alloc(128 * 128 / 2);
    __bf16* wnrt = (__bf16*)alloc(128 * 128 / 2);
    __bf16* wfct = (__bf16*)alloc(1024 * 128 / 2);
    int* outdeg_pp = (int*)alloc(NP);
    int* outdeg_pg = (int*)alloc(NP);
    int* outdeg_gp = (int*)alloc(NG);
    int* indeg_pp  = (int*)alloc(NP);
    int* indeg_gp  = (int*)alloc(NP);
    int* indeg_pg  = (int*)alloc(NG);
    int* fill      = (int*)alloc((size_t)NTOT * FS);
    int* row_ptr   = (int*)alloc(NTOT + 1);
    int2* edata    = (int2*)alloc((size_t)ETOT * 2);

    // zero only the fill counters
    hipMemsetAsync(fill, 0, (size_t)NTOT * FS * sizeof(int), stream);

    // degree histograms: HB blocks/job, LDS-private partials, plain stores; then merge
    hist_part_kernel<<<dim3(HB, 6), 1024, 0, stream>>>(
        src_pp, dst_pp, src_pg, dst_pg, src_gp, dst_gp, partial);
    hist_merge_kernel<<<dim3((20000 + 255) / 256, 6), 256, 0, stream>>>(
        partial, outdeg_pp, indeg_pp, outdeg_pg, indeg_pg, outdeg_gp, indeg_gp);
    scan_kernel<<<1, 1024, 0, stream>>>(indeg_pp, indeg_gp, indeg_pg, row_ptr);
    scatter_kernel<<<(ETOT + 255) / 256, 256, 0, stream>>>(
        src_pp, dst_pp, src_pg, dst_pg, src_gp, dst_gp,
        outdeg_pp, outdeg_pg, outdeg_gp, row_ptr, fill, edata);

    conv_x_kernel<<<dim3(5008, 2), 256, 0, stream>>>(x_protein, x_go, xpb, xgb);
    conv_w_kernel<<<dim3(512, 8), 256, 0, stream>>>(W1p, W1g, Wl_p, Wr_p, Wr_g, Wnl, Wnr, Wfc,
                                                    w1pt, w1gt, wlpt, wrpt, wrgt, wnlt, wnrt, wfct);

    // fused projections + l2norm -> xb (bf16): blocks [0,313) protein, [313,392) go
    {
        GJob p0 = { xpb, nullptr, w1pt, nullptr, b1p, nullptr, nullptr, nullptr, xb, NP, 128, 512, 16 };
        GJob p1 = { xgb, nullptr, w1gt, nullptr, b1g, nullptr, nullptr, nullptr,
                    xb + (size_t)NP * 128, NG, 128, 1024, 32 };
        gemm_bt<2, 0, 0, 2><<<392, 256, 0, stream>>>(p0, p1, 313);
    }

    // GCN aggregation for type attention (protein dst only)
    rst_agg_kernel<<<NP, 128, 0, stream>>>(xb, row_ptr, edata, indeg_pp, indeg_gp, rppb, rgpb);

    // fused ea: wpp = elu(x@Wl_p + rpp@Wr_p + ...); wgp = elu(x@Wl_p + rgp@Wr_g + ...)
    {
        GJob e0 = { xb, rppb, wlpt, wrpt, bl_p, br_p, wpp, nullptr, nullptr, NP, 128, 128, 4 };
        GJob e1 = { xb, rgpb, wlpt, wrgt, bl_p, br_g, wgp, nullptr, nullptr, NP, 128, 128, 4 };
        gemm_bt<1, 1, 0, 0><<<626, 256, 0, stream>>>(e0, e1, 313);
    }

    // type-level alpha weights (in-place over wpp/wgp)
    wa_kernel<<<(NP * DH + 255) / 256, 256, 0, stream>>>(indeg_pp, indeg_gp, wpp, wgp);

    // node attention projections: Ob(bf16) = x@Wnl+bnl = hl; O2(fp32) = x@Wnr+bnr = hr
    {
        GJob h0 = { xb, nullptr, wnlt, wnrt, bnl, bnr, nullptr, hr, hlb, NTOT, 128, 128, 4 };
        gemm_bt<0, 0, 1, 2><<<391, 256, 0, stream>>>(h0, h0, 1 << 30);
    }

    // node attention + aggregation -> haggb (bf16)
    node_attn_kernel<<<NTOT, 128, 0, stream>>>(xb, hlb, hr, wpp, wgp, indeg_pg, row_ptr, edata, haggb);

    // final classifier: out = hagg@Wfc + bfc
    {
        GJob o0 = { haggb, nullptr, wfct, nullptr, bfc, nullptr, out, nullptr, nullptr, NTOT, NCLS, 128, 4 };
        gemm_bt<0, 0, 0, 0><<<dim3(391, 8), 256, 0, stream>>>(o0, o0, 1 << 30);
    }

    (void)in_sizes; (void)n_in; (void)out_size; (void)ws_size;
}